// Round 1
// baseline (2282.583 us; speedup 1.0000x reference)
//
#include <hip/hip_runtime.h>

// LSTM_Seq2Dis: emb -> LSTM(rec-dropout) -> maxpool2 -> [relu FC + drop] x2 -> sigmoid FC
// B=64 T=128 H=50 V=8192.  Heavy part: two 4096x8192x8192 GEMMs -> bf16 MFMA.
// This revision: big GEMMs moved to a 256x256-tile 8-phase schedule (8 waves,
// counted vmcnt, setprio) per the verified m201 template; small K=64 GEMM keeps
// the 128x128 2-phase kernel.

#define Bc 64
#define Tc 128
#define Hc 50
#define Vc 8192
#define Mrows 4096   // B * T/2

typedef unsigned short u16;
typedef short bf16x8 __attribute__((ext_vector_type(8)));
typedef float f32x4 __attribute__((ext_vector_type(4)));

__device__ __forceinline__ u16 f2bf(float x) {
  union { float f; unsigned int u; } v; v.f = x;
  unsigned int r = v.u + 0x7fffu + ((v.u >> 16) & 1u);   // RNE
  return (u16)(r >> 16);
}

__device__ __forceinline__ void async_copy16(void* lds, const void* g) {
  __builtin_amdgcn_global_load_lds(
      (const __attribute__((address_space(1))) void*)g,
      (__attribute__((address_space(3))) void*)lds, 16, 0, 0);
}

__device__ __forceinline__ float sigmoidf(float x) {
  return 1.0f / (1.0f + __expf(-x));
}

// ---------------------------------------------------------------------------
// zx[t][b][j] = b[j] + sum_h E[tok[b][t]][h] * Wx[h][j]     (j in [0,200))
__global__ __launch_bounds__(256) void zx_kernel(
    const int* __restrict__ tok, const float* __restrict__ E,
    const float* __restrict__ Wx, const float* __restrict__ bvec,
    float* __restrict__ zx) {
  const int tb = blockIdx.x;              // tb = t*64 + b
  const int t = tb >> 6, b = tb & 63;
  __shared__ float e_s[Hc];
  const int id = tok[b * Tc + t];
  if (threadIdx.x < Hc) e_s[threadIdx.x] = E[id * Hc + threadIdx.x];
  __syncthreads();
  if (threadIdx.x < 4 * Hc) {
    float acc = bvec[threadIdx.x];
    #pragma unroll
    for (int h = 0; h < Hc; ++h) acc += e_s[h] * Wx[h * 200 + threadIdx.x];
    zx[(size_t)tb * 200 + threadIdx.x] = acc;
  }
}

// ---------------------------------------------------------------------------
// LSTM scan, one block per batch element b. Fused MaxPool1D(2) -> bf16 pooled
__global__ __launch_bounds__(256) void lstm_kernel(
    const float* __restrict__ zx, const float* __restrict__ U,
    const float* __restrict__ rec_mask, u16* __restrict__ pooled) {
  const int b = blockIdx.x;
  const int tid = threadIdx.x;
  __shared__ float Us[4 * Hc * Hc];    // 40 KB
  __shared__ float recm[4 * Hc];
  __shared__ float h_s[Hc], c_s[Hc], hprev[Hc];
  __shared__ float hm[4 * Hc], z_s[4 * Hc];

  for (int i = tid; i < 4 * Hc * Hc; i += 256) Us[i] = U[i];
  if (tid < 200) recm[tid] = rec_mask[(tid / Hc) * Bc * Hc + b * Hc + (tid % Hc)];
  if (tid < Hc) { h_s[tid] = 0.f; c_s[tid] = 0.f; }
  __syncthreads();

  for (int t = 0; t < Tc; ++t) {
    if (tid < 200) hm[tid] = h_s[tid % Hc] * recm[tid];
    __syncthreads();
    if (tid < 200) {
      const int g = tid / Hc, k = tid % Hc;
      float acc = zx[((size_t)t * Bc + b) * 200 + tid];
      const float* Ug = Us + g * Hc * Hc;
      const float* hmg = hm + g * Hc;
      #pragma unroll
      for (int h = 0; h < Hc; ++h) acc += hmg[h] * Ug[h * Hc + k];
      z_s[tid] = acc;
    }
    __syncthreads();
    if (tid < Hc) {
      const int k = tid;
      const float i_ = sigmoidf(z_s[k]);
      const float f_ = sigmoidf(z_s[Hc + k]);
      const float g_ = tanhf(z_s[2 * Hc + k]);
      const float o_ = sigmoidf(z_s[3 * Hc + k]);
      const float c = f_ * c_s[k] + i_ * g_;
      const float h = o_ * tanhf(c);
      c_s[k] = c; h_s[k] = h;
      if ((t & 1) != 0) {
        pooled[((size_t)b * 64 + (t >> 1)) * 64 + k] = f2bf(fmaxf(hprev[k], h));
      } else {
        hprev[k] = h;
      }
    }
    if ((t & 1) != 0 && tid >= Hc && tid < 64)
      pooled[((size_t)b * 64 + (t >> 1)) * 64 + tid] = 0;   // K-pad
    __syncthreads();
  }
}

// ---------------------------------------------------------------------------
// W1 [50][8192] f32 -> W1T [8192][64] bf16 (transpose, K zero-padded to 64)
__global__ __launch_bounds__(256) void w1t_kernel(
    const float* __restrict__ W1, u16* __restrict__ W1T) {
  const int idx = blockIdx.x * 256 + threadIdx.x;   // idx = n*64 + k
  const int n = idx >> 6, k = idx & 63;
  const float v = (k < Hc) ? W1[(size_t)k * Vc + n] : 0.f;
  W1T[idx] = f2bf(v);
}

// ---------------------------------------------------------------------------
// W [8192][8192] f32 -> WT [8192][8192] bf16 transposed ([n][k]).
__global__ __launch_bounds__(256) void wt_kernel(
    const float* __restrict__ W, u16* __restrict__ WT) {
  __shared__ float sm[128][65];
  const int t = threadIdx.x;
  const size_t k0 = (size_t)blockIdx.x * 128;
  const size_t n0 = (size_t)blockIdx.y * 64;
  {
    const int n = t & 63, kr = t >> 6;
    #pragma unroll
    for (int i = 0; i < 32; ++i) {
      const int k = i * 4 + kr;
      sm[k][n] = W[(k0 + k) * Vc + n0 + n];
    }
  }
  __syncthreads();
  {
    const int kk = (t & 63) * 2, nr = t >> 6;
    #pragma unroll
    for (int i = 0; i < 16; ++i) {
      const int nn = i * 4 + nr;
      ushort2 v;
      v.x = f2bf(sm[kk][nn]);
      v.y = f2bf(sm[kk + 1][nn]);
      *(ushort2*)&WT[(n0 + nn) * Vc + k0 + kk] = v;
    }
  }
}

// ---------------------------------------------------------------------------
// 128x128-tile 2-phase GEMM (kept for the K=64 first GEMM only).
template <bool SIGMOID>
__global__ __launch_bounds__(256, 2) void gemm_bt(
    const u16* __restrict__ A, const u16* __restrict__ Bt,
    const float* __restrict__ bias, const float* __restrict__ mask,
    void* __restrict__ Cout, const int M, const int N, const int K) {
  __shared__ u16 As[128 * 64];
  __shared__ u16 Bs[128 * 64];
  const int tid = threadIdx.x;
  const int wave = tid >> 6;
  const int lane = tid & 63;
  const int wr = (wave >> 1) << 6;
  const int wc = (wave & 1) << 6;
  const long tileM = (long)blockIdx.y * 128;
  const long tileN = (long)blockIdx.x * 128;

  const int lrow = lane >> 3;
  const int cg8 = (((lane & 7) ^ lrow) << 3);
  const u16* Ab = A + tileM * K;
  const u16* Bb = Bt + tileN * K;

  f32x4 acc[4][4] = {};

  for (int k0 = 0; k0 < K; k0 += 64) {
    #pragma unroll
    for (int q4 = 0; q4 < 4; ++q4) {
      const int r = (wave << 5) + (q4 << 3) + lrow;
      const int ldsoff = (wave * 4 + q4) << 10;
      async_copy16((char*)As + ldsoff, Ab + (long)r * K + k0 + cg8);
      async_copy16((char*)Bs + ldsoff, Bb + (long)r * K + k0 + cg8);
    }
    __syncthreads();
    #pragma unroll
    for (int kk = 0; kk < 64; kk += 32) {
      const int ch = (kk >> 3) + (lane >> 4);
      bf16x8 af[4], bf[4];
      #pragma unroll
      for (int i = 0; i < 4; ++i) {
        const int ra = wr + (i << 4) + (lane & 15);
        af[i] = *(const bf16x8*)(As + ra * 64 + ((ch ^ (ra & 7)) << 3));
      }
      #pragma unroll
      for (int j = 0; j < 4; ++j) {
        const int rb = wc + (j << 4) + (lane & 15);
        bf[j] = *(const bf16x8*)(Bs + rb * 64 + ((ch ^ (rb & 7)) << 3));
      }
      #pragma unroll
      for (int i = 0; i < 4; ++i)
        #pragma unroll
        for (int j = 0; j < 4; ++j)
          acc[i][j] = __builtin_amdgcn_mfma_f32_16x16x32_bf16(af[i], bf[j], acc[i][j], 0, 0, 0);
    }
    __syncthreads();
  }

  const int qrow = (lane >> 4) << 2;
  const int qcol = lane & 15;
  #pragma unroll
  for (int j = 0; j < 4; ++j) {
    const long col = tileN + wc + (j << 4) + qcol;
    const float bv = bias[col];
    #pragma unroll
    for (int i = 0; i < 4; ++i) {
      const long row0 = tileM + wr + (i << 4) + qrow;
      #pragma unroll
      for (int r = 0; r < 4; ++r) {
        const long off = (row0 + r) * N + col;
        const float z = acc[i][j][r] + bv;
        if constexpr (SIGMOID) {
          ((float*)Cout)[off] = sigmoidf(z);
        } else {
          ((u16*)Cout)[off] = f2bf(fmaxf(z, 0.f) * mask[off]);
        }
      }
    }
  }
}

// ---------------------------------------------------------------------------
// 256x256-tile 8-phase GEMM for the big K=8192 GEMMs.
// 8 waves (2M x 4N). Per-wave output 128x64 split across halves:
//   rows  mh*128 + wm*64 + i*16   (mh = M-half, i = 0..3)
//   cols  nh*128 + wn*32 + j*16   (nh = N-half, j = 0..1)
// so phase-quadrant (mh,nh) reads exactly A-half mh + B-half nh for ALL waves,
// letting each half-tile LDS region be restaged right after its last reader.
// Stage schedule (per K-tile T, phases q0..q3):
//   q0: Ah1(T+1)->buf[T^1]   q1: Bh1(T+1)->buf[T^1]
//   q2: Ah0(T+2)->buf[T]     q3: Bh0(T+2)->buf[T]
// Waits: vmcnt(6) at end of q0, vmcnt(8) at end of q3 (never 0 in the loop).
template <bool SIGMOID>
__global__ __launch_bounds__(512, 2) void gemm256(
    const u16* __restrict__ A, const u16* __restrict__ Bt,
    const float* __restrict__ bias, const float* __restrict__ mask,
    void* __restrict__ Cout, const int M, const int N, const int K) {
  __shared__ u16 As[2][16384];   // [buf][256 rows][64 k] bf16, 32 KB per buf
  __shared__ u16 Bs[2][16384];
  const int tid = threadIdx.x;
  const int wave = tid >> 6;
  const int lane = tid & 63;
  const int l15 = lane & 15;
  const int chb = lane >> 4;
  const int wm64 = ((wave >> 2) & 1) << 6;   // M sub-position within a half
  const int wn32 = (wave & 3) << 5;          // N sub-position within a half

  // XCD-aware swizzle (nwg = 512, divisible by 8 -> bijective)
  const int nwg = gridDim.x;
  const int cpx = nwg >> 3;
  const int bid = blockIdx.x;
  const int swz = (bid & 7) * cpx + (bid >> 3);
  const int ntN = N >> 8;
  const long tileM = (long)(swz / ntN) << 8;
  const long tileN = (long)(swz % ntN) << 8;

  const u16* Ab = A + tileM * K;
  const u16* Bb = Bt + tileN * K;

  // staging: 512 threads cover 64 rows x 64 k per issue; 2 issues per half-tile
  const int srow = tid >> 3;                          // 0..63 row within issue
  const int schunk = ((tid & 7) ^ (srow & 7)) << 3;   // pre-swizzled k offset
  const long srowK = (long)srow * K + schunk;
  const long K64 = (long)K << 6;                      // 64 rows stride
  const int stgoff = wave << 10;                      // wave-uniform LDS base
  const int nt = K >> 6;

  f32x4 acc[8][4] = {};

#define STG(DSTBASE, SRCB, KT, HH) do {                                   \
    const int _kt = (KT) < nt ? (KT) : nt - 1;                            \
    const u16* _s = (SRCB) + ((long)(HH) * 128) * K + srowK + ((long)_kt << 6); \
    char* _d = (char*)(DSTBASE) + (HH) * 16384 + stgoff;                  \
    async_copy16(_d, _s);                                                 \
    async_copy16(_d + 8192, _s + K64);                                    \
  } while (0)

  // prologue stream: Ah0(0) Bh0(0) Ah1(0) Bh1(0) Ah0(1) Bh0(1)  (12 loads)
  STG(As[0], Ab, 0, 0);
  STG(Bs[0], Bb, 0, 0);
  STG(As[0], Ab, 0, 1);
  STG(Bs[0], Bb, 0, 1);
  STG(As[1], Ab, 1, 0);
  STG(Bs[1], Bb, 1, 0);
  asm volatile("s_waitcnt vmcnt(8)" ::: "memory");   // Ah0(0),Bh0(0) landed
  __builtin_amdgcn_s_barrier();

#define PHASE(CUR, MH, NH, STAGE_STMT, WAIT_STMT) do {                    \
    bf16x8 af[2][4], bv[2][2];                                            \
    const u16* _A = As[CUR];                                              \
    const u16* _B = Bs[CUR];                                              \
    _Pragma("unroll")                                                     \
    for (int kc = 0; kc < 2; ++kc) {                                      \
      const int ch = (kc << 2) + chb;                                     \
      _Pragma("unroll")                                                   \
      for (int i = 0; i < 4; ++i) {                                       \
        const int ra = (MH) * 128 + wm64 + (i << 4) + l15;                \
        af[kc][i] = *(const bf16x8*)(_A + ra * 64 + ((ch ^ (ra & 7)) << 3)); \
      }                                                                   \
      _Pragma("unroll")                                                   \
      for (int j = 0; j < 2; ++j) {                                       \
        const int rb = (NH) * 128 + wn32 + (j << 4) + l15;                \
        bv[kc][j] = *(const bf16x8*)(_B + rb * 64 + ((ch ^ (rb & 7)) << 3)); \
      }                                                                   \
    }                                                                     \
    STAGE_STMT;                                                           \
    __builtin_amdgcn_s_barrier();                                         \
    asm volatile("s_waitcnt lgkmcnt(0)" ::: "memory");                    \
    __builtin_amdgcn_sched_barrier(0);                                    \
    __builtin_amdgcn_s_setprio(1);                                        \
    _Pragma("unroll")                                                     \
    for (int kc = 0; kc < 2; ++kc)                                        \
      _Pragma("unroll")                                                   \
      for (int i = 0; i < 4; ++i)                                         \
        _Pragma("unroll")                                                 \
        for (int j = 0; j < 2; ++j)                                       \
          acc[(MH) * 4 + i][(NH) * 2 + j] =                               \
              __builtin_amdgcn_mfma_f32_16x16x32_bf16(                    \
                  af[kc][i], bv[kc][j], acc[(MH) * 4 + i][(NH) * 2 + j],  \
                  0, 0, 0);                                               \
    __builtin_amdgcn_s_setprio(0);                                        \
    WAIT_STMT;                                                            \
    __builtin_amdgcn_s_barrier();                                         \
  } while (0)

  for (int T = 0; T < nt; T += 2) {
    // K-tile T (buf 0)
    PHASE(0, 0, 0, STG(As[1], Ab, T + 1, 1),
          asm volatile("s_waitcnt vmcnt(6)" ::: "memory"));
    PHASE(0, 0, 1, STG(Bs[1], Bb, T + 1, 1), (void)0);
    PHASE(0, 1, 0, STG(As[0], Ab, T + 2, 0), (void)0);
    PHASE(0, 1, 1, STG(Bs[0], Bb, T + 2, 0),
          asm volatile("s_waitcnt vmcnt(8)" ::: "memory"));
    // K-tile T+1 (buf 1)
    PHASE(1, 0, 0, STG(As[0], Ab, T + 2, 1),
          asm volatile("s_waitcnt vmcnt(6)" ::: "memory"));
    PHASE(1, 0, 1, STG(Bs[0], Bb, T + 2, 1), (void)0);
    PHASE(1, 1, 0, STG(As[1], Ab, T + 3, 0), (void)0);
    PHASE(1, 1, 1, STG(Bs[1], Bb, T + 3, 0),
          asm volatile("s_waitcnt vmcnt(8)" ::: "memory"));
  }

#undef PHASE
#undef STG

  // epilogue: C/D layout col=lane&15, row=(lane>>4)*4+reg
  const int qrow = (lane >> 4) << 2;
  #pragma unroll
  for (int nh = 0; nh < 2; ++nh) {
    #pragma unroll
    for (int j = 0; j < 2; ++j) {
      const long col = tileN + nh * 128 + wn32 + (j << 4) + l15;
      const float bvv = bias[col];
      #pragma unroll
      for (int mh = 0; mh < 2; ++mh) {
        #pragma unroll
        for (int i = 0; i < 4; ++i) {
          const long row0 = tileM + mh * 128 + wm64 + (i << 4) + qrow;
          #pragma unroll
          for (int r = 0; r < 4; ++r) {
            const long off = (row0 + r) * N + col;
            const float z = acc[mh * 4 + i][nh * 2 + j][r] + bvv;
            if constexpr (SIGMOID) {
              ((float*)Cout)[off] = sigmoidf(z);
            } else {
              ((u16*)Cout)[off] = f2bf(fmaxf(z, 0.f) * mask[off]);
            }
          }
        }
      }
    }
  }
}

// ---------------------------------------------------------------------------
extern "C" void kernel_launch(void* const* d_in, const int* in_sizes, int n_in,
                              void* d_out, int out_size, void* d_ws, size_t ws_size,
                              hipStream_t stream) {
  const int*   tok  = (const int*)  d_in[0];
  const float* E    = (const float*)d_in[1];
  const float* Wx   = (const float*)d_in[2];
  const float* U    = (const float*)d_in[3];
  const float* bvec = (const float*)d_in[4];
  const float* W1   = (const float*)d_in[5];
  const float* b1   = (const float*)d_in[6];
  const float* W1b  = (const float*)d_in[7];
  const float* W2   = (const float*)d_in[8];
  const float* b2   = (const float*)d_in[9];
  const float* recm = (const float*)d_in[10];
  const float* dm1  = (const float*)d_in[11];
  const float* dm2  = (const float*)d_in[12];
  float* out = (float*)d_out;

  char* w = (char*)d_ws;
  u16* Wt     = (u16*)w;  w += (size_t)Vc * Vc * 2;        // 128 MB (reused W1b/W2)
  u16* A1     = (u16*)w;  w += (size_t)Mrows * Vc * 2;     // 64 MB
  u16* A2     = (u16*)w;  w += (size_t)Mrows * Vc * 2;     // 64 MB
  u16* W1T    = (u16*)w;  w += (size_t)Vc * 64 * 2;        // 1 MB
  u16* pooled = (u16*)w;  w += (size_t)Mrows * 64 * 2;     // 0.5 MB
  float* zx   = (float*)w;                                  // 6.25 MB

  zx_kernel  <<<Bc * Tc, 256, 0, stream>>>(tok, E, Wx, bvec, zx);
  lstm_kernel<<<Bc, 256, 0, stream>>>(zx, U, recm, pooled);
  w1t_kernel <<<(Vc * 64) / 256, 256, 0, stream>>>(W1, W1T);
  // d1 = relu(pooled @ W1 + b1) * dmask1  -> A1 (bf16)   (K=64: 128^2 kernel)
  gemm_bt<false><<<dim3(Vc / 128, Mrows / 128), 256, 0, stream>>>(
      pooled, W1T, b1, dm1, A1, Mrows, Vc, 64);
  // d2 = relu(A1 @ W1b + b1) * dmask2 -> A2 (bf16)       (256^2 8-phase)
  wt_kernel<<<dim3(Vc / 128, Vc / 64), 256, 0, stream>>>(W1b, Wt);
  gemm256<false><<<dim3((Mrows / 256) * (Vc / 256)), 512, 0, stream>>>(
      A1, Wt, b1, dm2, A2, Mrows, Vc, Vc);
  // prbs = sigmoid(A2 @ W2 + b2) -> out (f32)            (256^2 8-phase)
  wt_kernel<<<dim3(Vc / 128, Vc / 64), 256, 0, stream>>>(W2, Wt);
  gemm256<true><<<dim3((Mrows / 256) * (Vc / 256)), 512, 0, stream>>>(
      A2, Wt, b2, nullptr, out, Mrows, Vc, Vc);
}

// Round 2
// 2171.472 us; speedup vs baseline: 1.0512x; 1.0512x over previous
//
#include <hip/hip_runtime.h>

// LSTM_Seq2Dis: emb -> LSTM(rec-dropout) -> maxpool2 -> [relu FC + drop] x2 -> sigmoid FC
// B=64 T=128 H=50 V=8192.  Heavy part: two 4096x8192x8192 GEMMs -> bf16 MFMA.
// Round 2: gemm256 phases Gray-coded ((0,0)->(0,1)->(1,1)->(1,0)) with operands
// held in registers across phases -> LDS read volume per K-tile drops 48->24
// ds_read_b128 per wave (the round-1 regression was 2x redundant LDS reads
// serialized against MFMA by the mid-phase lgkmcnt(0)).

#define Bc 64
#define Tc 128
#define Hc 50
#define Vc 8192
#define Mrows 4096   // B * T/2

typedef unsigned short u16;
typedef short bf16x8 __attribute__((ext_vector_type(8)));
typedef float f32x4 __attribute__((ext_vector_type(4)));

__device__ __forceinline__ u16 f2bf(float x) {
  union { float f; unsigned int u; } v; v.f = x;
  unsigned int r = v.u + 0x7fffu + ((v.u >> 16) & 1u);   // RNE
  return (u16)(r >> 16);
}

__device__ __forceinline__ void async_copy16(void* lds, const void* g) {
  __builtin_amdgcn_global_load_lds(
      (const __attribute__((address_space(1))) void*)g,
      (__attribute__((address_space(3))) void*)lds, 16, 0, 0);
}

__device__ __forceinline__ float sigmoidf(float x) {
  return 1.0f / (1.0f + __expf(-x));
}

// ---------------------------------------------------------------------------
// zx[t][b][j] = b[j] + sum_h E[tok[b][t]][h] * Wx[h][j]     (j in [0,200))
__global__ __launch_bounds__(256) void zx_kernel(
    const int* __restrict__ tok, const float* __restrict__ E,
    const float* __restrict__ Wx, const float* __restrict__ bvec,
    float* __restrict__ zx) {
  const int tb = blockIdx.x;              // tb = t*64 + b
  const int t = tb >> 6, b = tb & 63;
  __shared__ float e_s[Hc];
  const int id = tok[b * Tc + t];
  if (threadIdx.x < Hc) e_s[threadIdx.x] = E[id * Hc + threadIdx.x];
  __syncthreads();
  if (threadIdx.x < 4 * Hc) {
    float acc = bvec[threadIdx.x];
    #pragma unroll
    for (int h = 0; h < Hc; ++h) acc += e_s[h] * Wx[h * 200 + threadIdx.x];
    zx[(size_t)tb * 200 + threadIdx.x] = acc;
  }
}

// ---------------------------------------------------------------------------
// LSTM scan, one block per batch element b. Fused MaxPool1D(2) -> bf16 pooled
__global__ __launch_bounds__(256) void lstm_kernel(
    const float* __restrict__ zx, const float* __restrict__ U,
    const float* __restrict__ rec_mask, u16* __restrict__ pooled) {
  const int b = blockIdx.x;
  const int tid = threadIdx.x;
  __shared__ float Us[4 * Hc * Hc];    // 40 KB
  __shared__ float recm[4 * Hc];
  __shared__ float h_s[Hc], c_s[Hc], hprev[Hc];
  __shared__ float hm[4 * Hc], z_s[4 * Hc];

  for (int i = tid; i < 4 * Hc * Hc; i += 256) Us[i] = U[i];
  if (tid < 200) recm[tid] = rec_mask[(tid / Hc) * Bc * Hc + b * Hc + (tid % Hc)];
  if (tid < Hc) { h_s[tid] = 0.f; c_s[tid] = 0.f; }
  __syncthreads();

  for (int t = 0; t < Tc; ++t) {
    if (tid < 200) hm[tid] = h_s[tid % Hc] * recm[tid];
    __syncthreads();
    if (tid < 200) {
      const int g = tid / Hc, k = tid % Hc;
      float acc = zx[((size_t)t * Bc + b) * 200 + tid];
      const float* Ug = Us + g * Hc * Hc;
      const float* hmg = hm + g * Hc;
      #pragma unroll
      for (int h = 0; h < Hc; ++h) acc += hmg[h] * Ug[h * Hc + k];
      z_s[tid] = acc;
    }
    __syncthreads();
    if (tid < Hc) {
      const int k = tid;
      const float i_ = sigmoidf(z_s[k]);
      const float f_ = sigmoidf(z_s[Hc + k]);
      const float g_ = tanhf(z_s[2 * Hc + k]);
      const float o_ = sigmoidf(z_s[3 * Hc + k]);
      const float c = f_ * c_s[k] + i_ * g_;
      const float h = o_ * tanhf(c);
      c_s[k] = c; h_s[k] = h;
      if ((t & 1) != 0) {
        pooled[((size_t)b * 64 + (t >> 1)) * 64 + k] = f2bf(fmaxf(hprev[k], h));
      } else {
        hprev[k] = h;
      }
    }
    if ((t & 1) != 0 && tid >= Hc && tid < 64)
      pooled[((size_t)b * 64 + (t >> 1)) * 64 + tid] = 0;   // K-pad
    __syncthreads();
  }
}

// ---------------------------------------------------------------------------
// W1 [50][8192] f32 -> W1T [8192][64] bf16 (transpose, K zero-padded to 64)
__global__ __launch_bounds__(256) void w1t_kernel(
    const float* __restrict__ W1, u16* __restrict__ W1T) {
  const int idx = blockIdx.x * 256 + threadIdx.x;   // idx = n*64 + k
  const int n = idx >> 6, k = idx & 63;
  const float v = (k < Hc) ? W1[(size_t)k * Vc + n] : 0.f;
  W1T[idx] = f2bf(v);
}

// ---------------------------------------------------------------------------
// W [8192][8192] f32 -> WT [8192][8192] bf16 transposed ([n][k]).
__global__ __launch_bounds__(256) void wt_kernel(
    const float* __restrict__ W, u16* __restrict__ WT) {
  __shared__ float sm[128][65];
  const int t = threadIdx.x;
  const size_t k0 = (size_t)blockIdx.x * 128;
  const size_t n0 = (size_t)blockIdx.y * 64;
  {
    const int n = t & 63, kr = t >> 6;
    #pragma unroll
    for (int i = 0; i < 32; ++i) {
      const int k = i * 4 + kr;
      sm[k][n] = W[(k0 + k) * Vc + n0 + n];
    }
  }
  __syncthreads();
  {
    const int kk = (t & 63) * 2, nr = t >> 6;
    #pragma unroll
    for (int i = 0; i < 16; ++i) {
      const int nn = i * 4 + nr;
      ushort2 v;
      v.x = f2bf(sm[kk][nn]);
      v.y = f2bf(sm[kk + 1][nn]);
      *(ushort2*)&WT[(n0 + nn) * Vc + k0 + kk] = v;
    }
  }
}

// ---------------------------------------------------------------------------
// 128x128-tile 2-phase GEMM (kept for the K=64 first GEMM only).
template <bool SIGMOID>
__global__ __launch_bounds__(256, 2) void gemm_bt(
    const u16* __restrict__ A, const u16* __restrict__ Bt,
    const float* __restrict__ bias, const float* __restrict__ mask,
    void* __restrict__ Cout, const int M, const int N, const int K) {
  __shared__ u16 As[128 * 64];
  __shared__ u16 Bs[128 * 64];
  const int tid = threadIdx.x;
  const int wave = tid >> 6;
  const int lane = tid & 63;
  const int wr = (wave >> 1) << 6;
  const int wc = (wave & 1) << 6;
  const long tileM = (long)blockIdx.y * 128;
  const long tileN = (long)blockIdx.x * 128;

  const int lrow = lane >> 3;
  const int cg8 = (((lane & 7) ^ lrow) << 3);
  const u16* Ab = A + tileM * K;
  const u16* Bb = Bt + tileN * K;

  f32x4 acc[4][4] = {};

  for (int k0 = 0; k0 < K; k0 += 64) {
    #pragma unroll
    for (int q4 = 0; q4 < 4; ++q4) {
      const int r = (wave << 5) + (q4 << 3) + lrow;
      const int ldsoff = (wave * 4 + q4) << 10;
      async_copy16((char*)As + ldsoff, Ab + (long)r * K + k0 + cg8);
      async_copy16((char*)Bs + ldsoff, Bb + (long)r * K + k0 + cg8);
    }
    __syncthreads();
    #pragma unroll
    for (int kk = 0; kk < 64; kk += 32) {
      const int ch = (kk >> 3) + (lane >> 4);
      bf16x8 af[4], bf[4];
      #pragma unroll
      for (int i = 0; i < 4; ++i) {
        const int ra = wr + (i << 4) + (lane & 15);
        af[i] = *(const bf16x8*)(As + ra * 64 + ((ch ^ (ra & 7)) << 3));
      }
      #pragma unroll
      for (int j = 0; j < 4; ++j) {
        const int rb = wc + (j << 4) + (lane & 15);
        bf[j] = *(const bf16x8*)(Bs + rb * 64 + ((ch ^ (rb & 7)) << 3));
      }
      #pragma unroll
      for (int i = 0; i < 4; ++i)
        #pragma unroll
        for (int j = 0; j < 4; ++j)
          acc[i][j] = __builtin_amdgcn_mfma_f32_16x16x32_bf16(af[i], bf[j], acc[i][j], 0, 0, 0);
    }
    __syncthreads();
  }

  const int qrow = (lane >> 4) << 2;
  const int qcol = lane & 15;
  #pragma unroll
  for (int j = 0; j < 4; ++j) {
    const long col = tileN + wc + (j << 4) + qcol;
    const float bv = bias[col];
    #pragma unroll
    for (int i = 0; i < 4; ++i) {
      const long row0 = tileM + wr + (i << 4) + qrow;
      #pragma unroll
      for (int r = 0; r < 4; ++r) {
        const long off = (row0 + r) * N + col;
        const float z = acc[i][j][r] + bv;
        if constexpr (SIGMOID) {
          ((float*)Cout)[off] = sigmoidf(z);
        } else {
          ((u16*)Cout)[off] = f2bf(fmaxf(z, 0.f) * mask[off]);
        }
      }
    }
  }
}

// ---------------------------------------------------------------------------
// 256x256-tile 8-phase GEMM (Gray-code quadrants, register-held operands).
// 8 waves (2M x 4N); per-wave output 128x64 split across tile halves:
//   rows  mh*128 + wm64 + i*16,  cols  nh*128 + wn32 + j*16
// Per K-tile (4 phases, Gray order):
//   q0 (0,0): LDS-read A0(12 incl B0) ; no stage          ; MFMA acc[0..3][0..1]
//   q1 (0,1): LDS-read B1 (4)        ; stage A0(T+2)     ; MFMA acc[0..3][2..3]
//   q2 (1,1): LDS-read A1 (8)        ; stage B0,B1(T+2)  ; MFMA acc[4..7][2..3]
//   q3 (1,0): no LDS reads (regs)    ; stage A1(T+2)     ; MFMA acc[4..7][0..1]
// vmcnt(10) at end of q1 and q3 only (8..16 loads in flight, never drained).
template <bool SIGMOID>
__global__ __launch_bounds__(512, 2) void gemm256(
    const u16* __restrict__ A, const u16* __restrict__ Bt,
    const float* __restrict__ bias, const float* __restrict__ mask,
    void* __restrict__ Cout, const int M, const int N, const int K) {
  __shared__ u16 As[2][16384];   // [buf][256 rows][64 k] bf16, 32 KB per buf
  __shared__ u16 Bs[2][16384];
  const int tid = threadIdx.x;
  const int wave = tid >> 6;
  const int lane = tid & 63;
  const int l15 = lane & 15;
  const int chb = lane >> 4;
  const int wm64 = ((wave >> 2) & 1) << 6;   // M sub-position within a half
  const int wn32 = (wave & 3) << 5;          // N sub-position within a half

  // XCD-aware swizzle (nwg = 512, divisible by 8 -> bijective)
  const int nwg = gridDim.x;
  const int cpx = nwg >> 3;
  const int bid = blockIdx.x;
  const int swz = (bid & 7) * cpx + (bid >> 3);
  const int ntN = N >> 8;
  const long tileM = (long)(swz / ntN) << 8;
  const long tileN = (long)(swz % ntN) << 8;

  const u16* Ab = A + tileM * K;
  const u16* Bb = Bt + tileN * K;

  // staging: 512 threads cover 64 rows x 64 k per issue; 2 issues per half-tile
  const int srow = tid >> 3;                          // 0..63 row within issue
  const int schunk = ((tid & 7) ^ (srow & 7)) << 3;   // pre-swizzled k offset
  const long srowK = (long)srow * K + schunk;
  const long K64 = (long)K << 6;                      // 64 rows stride
  const int stgoff = wave << 10;                      // wave-uniform LDS base
  const int nt = K >> 6;

  f32x4 acc[8][4] = {};
  bf16x8 af[2][4], bv0[2][2], bv1[2][2];

#define STG(DSTBASE, SRCB, KT, HH) do {                                   \
    const int _kt = (KT) < nt ? (KT) : nt - 1;                            \
    const u16* _s = (SRCB) + ((long)(HH) * 128) * K + srowK + ((long)_kt << 6); \
    char* _d = (char*)(DSTBASE) + (HH) * 16384 + stgoff;                  \
    async_copy16(_d, _s);                                                 \
    async_copy16(_d + 8192, _s + K64);                                    \
  } while (0)

#define LDA(CUR, MH) do {                                                 \
    const u16* _A = As[CUR];                                              \
    _Pragma("unroll")                                                     \
    for (int kc = 0; kc < 2; ++kc) {                                      \
      const int ch = (kc << 2) + chb;                                     \
      _Pragma("unroll")                                                   \
      for (int i = 0; i < 4; ++i) {                                       \
        const int ra = (MH) * 128 + wm64 + (i << 4) + l15;                \
        af[kc][i] = *(const bf16x8*)(_A + ra * 64 + ((ch ^ (ra & 7)) << 3)); \
      }                                                                   \
    }                                                                     \
  } while (0)

#define LDB(CUR, NH, BV) do {                                             \
    const u16* _B = Bs[CUR];                                              \
    _Pragma("unroll")                                                     \
    for (int kc = 0; kc < 2; ++kc) {                                      \
      const int ch = (kc << 2) + chb;                                     \
      _Pragma("unroll")                                                   \
      for (int j = 0; j < 2; ++j) {                                       \
        const int rb = (NH) * 128 + wn32 + (j << 4) + l15;                \
        BV[kc][j] = *(const bf16x8*)(_B + rb * 64 + ((ch ^ (rb & 7)) << 3)); \
      }                                                                   \
    }                                                                     \
  } while (0)

#define MM(MH, NB, BV) do {                                               \
    __builtin_amdgcn_s_setprio(1);                                        \
    _Pragma("unroll")                                                     \
    for (int kc = 0; kc < 2; ++kc)                                        \
      _Pragma("unroll")                                                   \
      for (int i = 0; i < 4; ++i)                                         \
        _Pragma("unroll")                                                 \
        for (int j = 0; j < 2; ++j)                                       \
          acc[(MH) * 4 + i][(NB) + j] =                                   \
              __builtin_amdgcn_mfma_f32_16x16x32_bf16(                    \
                  af[kc][i], BV[kc][j], acc[(MH) * 4 + i][(NB) + j],      \
                  0, 0, 0);                                               \
    __builtin_amdgcn_s_setprio(0);                                        \
  } while (0)

#define BAR() __builtin_amdgcn_s_barrier()
#define WLG0() do {                                                       \
    asm volatile("s_waitcnt lgkmcnt(0)" ::: "memory");                    \
    __builtin_amdgcn_sched_barrier(0);                                    \
  } while (0)

  // prologue: stage tiles 0 and 1 fully (16 loads), wait tile 0 landed
  STG(As[0], Ab, 0, 0);   // A0(0)
  STG(Bs[0], Bb, 0, 0);   // B0(0)
  STG(Bs[0], Bb, 0, 1);   // B1(0)
  STG(As[0], Ab, 0, 1);   // A1(0)
  STG(As[1], Ab, 1, 0);
  STG(Bs[1], Bb, 1, 0);
  STG(Bs[1], Bb, 1, 1);
  STG(As[1], Ab, 1, 1);
  asm volatile("s_waitcnt vmcnt(8)" ::: "memory");
  BAR();

#define TILE4(CUR, TNEXT) do {                                            \
    /* q0 (0,0): read A0+B0 */                                            \
    LDA(CUR, 0);                                                          \
    LDB(CUR, 0, bv0);                                                     \
    asm volatile("s_waitcnt lgkmcnt(8)" ::: "memory");                    \
    BAR(); WLG0();                                                        \
    MM(0, 0, bv0);                                                        \
    BAR();                                                                \
    /* q1 (0,1): read B1, stage A0(T+2) */                                \
    LDB(CUR, 1, bv1);                                                     \
    STG(As[CUR], Ab, TNEXT, 0);                                           \
    BAR(); WLG0();                                                        \
    MM(0, 2, bv1);                                                        \
    asm volatile("s_waitcnt vmcnt(10)" ::: "memory");                     \
    BAR();                                                                \
    /* q2 (1,1): read A1, stage B0,B1(T+2) */                             \
    LDA(CUR, 1);                                                          \
    STG(Bs[CUR], Bb, TNEXT, 0);                                           \
    STG(Bs[CUR], Bb, TNEXT, 1);                                           \
    BAR(); WLG0();                                                        \
    MM(1, 2, bv1);                                                        \
    BAR();                                                                \
    /* q3 (1,0): regs only, stage A1(T+2) */                              \
    STG(As[CUR], Ab, TNEXT, 1);                                           \
    BAR();                                                                \
    __builtin_amdgcn_sched_barrier(0);                                    \
    MM(1, 0, bv0);                                                        \
    asm volatile("s_waitcnt vmcnt(10)" ::: "memory");                     \
    BAR();                                                                \
  } while (0)

  for (int T = 0; T < nt; T += 2) {
    TILE4(0, T + 2);
    TILE4(1, T + 3);
  }

#undef TILE4
#undef WLG0
#undef BAR
#undef MM
#undef LDB
#undef LDA
#undef STG

  // epilogue: C/D layout col=lane&15, row=(lane>>4)*4+reg
  const int qrow = (lane >> 4) << 2;
  #pragma unroll
  for (int nh = 0; nh < 2; ++nh) {
    #pragma unroll
    for (int j = 0; j < 2; ++j) {
      const long col = tileN + nh * 128 + wn32 + (j << 4) + l15;
      const float bvv = bias[col];
      #pragma unroll
      for (int mh = 0; mh < 2; ++mh) {
        #pragma unroll
        for (int i = 0; i < 4; ++i) {
          const long row0 = tileM + mh * 128 + wm64 + (i << 4) + qrow;
          #pragma unroll
          for (int r = 0; r < 4; ++r) {
            const long off = (row0 + r) * N + col;
            const float z = acc[mh * 4 + i][nh * 2 + j][r] + bvv;
            if constexpr (SIGMOID) {
              ((float*)Cout)[off] = sigmoidf(z);
            } else {
              ((u16*)Cout)[off] = f2bf(fmaxf(z, 0.f) * mask[off]);
            }
          }
        }
      }
    }
  }
}

// ---------------------------------------------------------------------------
extern "C" void kernel_launch(void* const* d_in, const int* in_sizes, int n_in,
                              void* d_out, int out_size, void* d_ws, size_t ws_size,
                              hipStream_t stream) {
  const int*   tok  = (const int*)  d_in[0];
  const float* E    = (const float*)d_in[1];
  const float* Wx   = (const float*)d_in[2];
  const float* U    = (const float*)d_in[3];
  const float* bvec = (const float*)d_in[4];
  const float* W1   = (const float*)d_in[5];
  const float* b1   = (const float*)d_in[6];
  const float* W1b  = (const float*)d_in[7];
  const float* W2   = (const float*)d_in[8];
  const float* b2   = (const float*)d_in[9];
  const float* recm = (const float*)d_in[10];
  const float* dm1  = (const float*)d_in[11];
  const float* dm2  = (const float*)d_in[12];
  float* out = (float*)d_out;

  char* w = (char*)d_ws;
  u16* Wt     = (u16*)w;  w += (size_t)Vc * Vc * 2;        // 128 MB (reused W1b/W2)
  u16* A1     = (u16*)w;  w += (size_t)Mrows * Vc * 2;     // 64 MB
  u16* A2     = (u16*)w;  w += (size_t)Mrows * Vc * 2;     // 64 MB
  u16* W1T    = (u16*)w;  w += (size_t)Vc * 64 * 2;        // 1 MB
  u16* pooled = (u16*)w;  w += (size_t)Mrows * 64 * 2;     // 0.5 MB
  float* zx   = (float*)w;                                  // 6.25 MB

  zx_kernel  <<<Bc * Tc, 256, 0, stream>>>(tok, E, Wx, bvec, zx);
  lstm_kernel<<<Bc, 256, 0, stream>>>(zx, U, recm, pooled);
  w1t_kernel <<<(Vc * 64) / 256, 256, 0, stream>>>(W1, W1T);
  // d1 = relu(pooled @ W1 + b1) * dmask1  -> A1 (bf16)   (K=64: 128^2 kernel)
  gemm_bt<false><<<dim3(Vc / 128, Mrows / 128), 256, 0, stream>>>(
      pooled, W1T, b1, dm1, A1, Mrows, Vc, 64);
  // d2 = relu(A1 @ W1b + b1) * dmask2 -> A2 (bf16)       (256^2 Gray 8-phase)
  wt_kernel<<<dim3(Vc / 128, Vc / 64), 256, 0, stream>>>(W1b, Wt);
  gemm256<false><<<dim3((Mrows / 256) * (Vc / 256)), 512, 0, stream>>>(
      A1, Wt, b1, dm2, A2, Mrows, Vc, Vc);
  // prbs = sigmoid(A2 @ W2 + b2) -> out (f32)            (256^2 Gray 8-phase)
  wt_kernel<<<dim3(Vc / 128, Vc / 64), 256, 0, stream>>>(W2, Wt);
  gemm256<true><<<dim3((Mrows / 256) * (Vc / 256)), 512, 0, stream>>>(
      A2, Wt, b2, nullptr, out, Mrows, Vc, Vc);
}

// Round 4
// 2039.919 us; speedup vs baseline: 1.1190x; 1.0645x over previous
//
#include <hip/hip_runtime.h>

// LSTM_Seq2Dis: emb -> LSTM(rec-dropout) -> maxpool2 -> [relu FC + drop] x2 -> sigmoid FC
// B=64 T=128 H=50 V=8192.  Heavy part: two 4096x8192x8192 GEMMs -> bf16 MFMA.
// Round 4 = round 3 resubmit (container infra failure, no kernel verdict).
// Big GEMMs: proven 2-phase 128^2 kernel. New wt_kernel: 1-KB/wave float4
// reads, XOR-swizzled LDS (b128 writes conflict-free, col reads 2-way=free),
// ushort8 writes in 128-B contiguous segments.

#define Bc 64
#define Tc 128
#define Hc 50
#define Vc 8192
#define Mrows 4096   // B * T/2

typedef unsigned short u16;
typedef short bf16x8 __attribute__((ext_vector_type(8)));
typedef u16 u16x8 __attribute__((ext_vector_type(8)));
typedef float f32x4 __attribute__((ext_vector_type(4)));

__device__ __forceinline__ u16 f2bf(float x) {
  union { float f; unsigned int u; } v; v.f = x;
  unsigned int r = v.u + 0x7fffu + ((v.u >> 16) & 1u);   // RNE
  return (u16)(r >> 16);
}

__device__ __forceinline__ void async_copy16(void* lds, const void* g) {
  __builtin_amdgcn_global_load_lds(
      (const __attribute__((address_space(1))) void*)g,
      (__attribute__((address_space(3))) void*)lds, 16, 0, 0);
}

__device__ __forceinline__ float sigmoidf(float x) {
  return 1.0f / (1.0f + __expf(-x));
}

// ---------------------------------------------------------------------------
// zx[t][b][j] = b[j] + sum_h E[tok[b][t]][h] * Wx[h][j]     (j in [0,200))
__global__ __launch_bounds__(256) void zx_kernel(
    const int* __restrict__ tok, const float* __restrict__ E,
    const float* __restrict__ Wx, const float* __restrict__ bvec,
    float* __restrict__ zx) {
  const int tb = blockIdx.x;              // tb = t*64 + b
  const int t = tb >> 6, b = tb & 63;
  __shared__ float e_s[Hc];
  const int id = tok[b * Tc + t];
  if (threadIdx.x < Hc) e_s[threadIdx.x] = E[id * Hc + threadIdx.x];
  __syncthreads();
  if (threadIdx.x < 4 * Hc) {
    float acc = bvec[threadIdx.x];
    #pragma unroll
    for (int h = 0; h < Hc; ++h) acc += e_s[h] * Wx[h * 200 + threadIdx.x];
    zx[(size_t)tb * 200 + threadIdx.x] = acc;
  }
}

// ---------------------------------------------------------------------------
// LSTM scan, one block per batch element b. Fused MaxPool1D(2) -> bf16 pooled
__global__ __launch_bounds__(256) void lstm_kernel(
    const float* __restrict__ zx, const float* __restrict__ U,
    const float* __restrict__ rec_mask, u16* __restrict__ pooled) {
  const int b = blockIdx.x;
  const int tid = threadIdx.x;
  __shared__ float Us[4 * Hc * Hc];    // 40 KB
  __shared__ float recm[4 * Hc];
  __shared__ float h_s[Hc], c_s[Hc], hprev[Hc];
  __shared__ float hm[4 * Hc], z_s[4 * Hc];

  for (int i = tid; i < 4 * Hc * Hc; i += 256) Us[i] = U[i];
  if (tid < 200) recm[tid] = rec_mask[(tid / Hc) * Bc * Hc + b * Hc + (tid % Hc)];
  if (tid < Hc) { h_s[tid] = 0.f; c_s[tid] = 0.f; }
  __syncthreads();

  for (int t = 0; t < Tc; ++t) {
    if (tid < 200) hm[tid] = h_s[tid % Hc] * recm[tid];
    __syncthreads();
    if (tid < 200) {
      const int g = tid / Hc, k = tid % Hc;
      float acc = zx[((size_t)t * Bc + b) * 200 + tid];
      const float* Ug = Us + g * Hc * Hc;
      const float* hmg = hm + g * Hc;
      #pragma unroll
      for (int h = 0; h < Hc; ++h) acc += hmg[h] * Ug[h * Hc + k];
      z_s[tid] = acc;
    }
    __syncthreads();
    if (tid < Hc) {
      const int k = tid;
      const float i_ = sigmoidf(z_s[k]);
      const float f_ = sigmoidf(z_s[Hc + k]);
      const float g_ = tanhf(z_s[2 * Hc + k]);
      const float o_ = sigmoidf(z_s[3 * Hc + k]);
      const float c = f_ * c_s[k] + i_ * g_;
      const float h = o_ * tanhf(c);
      c_s[k] = c; h_s[k] = h;
      if ((t & 1) != 0) {
        pooled[((size_t)b * 64 + (t >> 1)) * 64 + k] = f2bf(fmaxf(hprev[k], h));
      } else {
        hprev[k] = h;
      }
    }
    if ((t & 1) != 0 && tid >= Hc && tid < 64)
      pooled[((size_t)b * 64 + (t >> 1)) * 64 + tid] = 0;   // K-pad
    __syncthreads();
  }
}

// ---------------------------------------------------------------------------
// W1 [50][8192] f32 -> W1T [8192][64] bf16 (transpose, K zero-padded to 64)
__global__ __launch_bounds__(256) void w1t_kernel(
    const float* __restrict__ W1, u16* __restrict__ W1T) {
  const int idx = blockIdx.x * 256 + threadIdx.x;   // idx = n*64 + k
  const int n = idx >> 6, k = idx & 63;
  const float v = (k < Hc) ? W1[(size_t)k * Vc + n] : 0.f;
  W1T[idx] = f2bf(v);
}

// ---------------------------------------------------------------------------
// W [8192][8192] f32 -> WT [8192][8192] bf16 transposed ([n][k]).
// Tile 64(k) x 256(n). Reads: 1 KB contiguous per wave (float4, lanes span n).
// LDS: f32 [64][256], float4 stored at XOR-swizzled chunk
//   chunk' = (n>>2) ^ ((k>>3)&7)
// -> b128 writes conflict-free (chunk' is a lane permutation at fixed k);
// -> column reads (8 lanes span k>>3=0..7) hit 8 distinct banks, 2-way total.
// Writes: ushort8 per lane; 8 lanes cover 128 B contiguous per n-row.
__global__ __launch_bounds__(256) void wt_kernel(
    const float* __restrict__ W, u16* __restrict__ WT) {
  __shared__ float sm[64 * 256];   // 64 KB
  const int t = threadIdx.x;
  const size_t k0 = (size_t)blockIdx.x * 64;
  const size_t n0 = (size_t)blockIdx.y * 256;
  {
    const int nc = (t & 63) * 4;       // lane n-offset (float4)
    const int kw = t >> 6;             // wave -> k row within group of 4
    #pragma unroll
    for (int i = 0; i < 16; ++i) {
      const int k = i * 4 + kw;
      const float4 v = *(const float4*)(W + (k0 + k) * Vc + n0 + nc);
      const int ch = (nc >> 2) ^ ((k >> 3) & 7);
      *(float4*)&sm[k * 256 + ch * 4] = v;
    }
  }
  __syncthreads();
  {
    const int kk = (t & 7) * 8;        // 8 lanes cover k 0..63 (128 B out)
    const int nr = t >> 3;             // 0..31
    #pragma unroll
    for (int i = 0; i < 8; ++i) {
      const int n = i * 32 + nr;
      const int chx = (n >> 2) ^ (t & 7);   // (k>>3)&7 == t&7 for this lane
      const int nlo = n & 3;
      u16x8 o;
      #pragma unroll
      for (int c = 0; c < 8; ++c) {
        const int k = kk + c;
        o[c] = f2bf(sm[k * 256 + chx * 4 + nlo]);
      }
      *(u16x8*)&WT[(n0 + n) * Vc + k0 + kk] = o;
    }
  }
}

// ---------------------------------------------------------------------------
// C[M][N] = epilogue(A[M][K] @ Bt[N][K]^T + bias)
//   SIGMOID=false: relu(z) * mask -> bf16 store
//   SIGMOID=true : sigmoid(z)     -> f32 store
// 128x128 tile, BK=64, 4 waves x (4x4) mfma_f32_16x16x32_bf16.
// global_load_lds(16B) staging; XOR-swizzled LDS chunks (slot = chunk ^ (row&7))
// so ds_read_b128 fragment loads are conflict-free.
template <bool SIGMOID>
__global__ __launch_bounds__(256, 2) void gemm_bt(
    const u16* __restrict__ A, const u16* __restrict__ Bt,
    const float* __restrict__ bias, const float* __restrict__ mask,
    void* __restrict__ Cout, const int M, const int N, const int K) {
  __shared__ u16 As[128 * 64];
  __shared__ u16 Bs[128 * 64];
  const int tid = threadIdx.x;
  const int wave = tid >> 6;
  const int lane = tid & 63;
  const int wr = (wave >> 1) << 6;    // 0 / 64
  const int wc = (wave & 1) << 6;     // 0 / 64
  const long tileM = (long)blockIdx.y * 128;
  const long tileN = (long)blockIdx.x * 128;

  // staging geometry: issue q = wave*4+q4 covers rows q*8..q*8+7 (row=128B)
  const int lrow = lane >> 3;                       // 0..7
  const int cg8 = (((lane & 7) ^ lrow) << 3);       // swizzled k-elem offset
  const u16* Ab = A + tileM * K;
  const u16* Bb = Bt + tileN * K;

  f32x4 acc[4][4] = {};

  for (int k0 = 0; k0 < K; k0 += 64) {
    #pragma unroll
    for (int q4 = 0; q4 < 4; ++q4) {
      const int r = (wave << 5) + (q4 << 3) + lrow;
      const int ldsoff = (wave * 4 + q4) << 10;     // bytes
      async_copy16((char*)As + ldsoff, Ab + (long)r * K + k0 + cg8);
      async_copy16((char*)Bs + ldsoff, Bb + (long)r * K + k0 + cg8);
    }
    __syncthreads();
    #pragma unroll
    for (int kk = 0; kk < 64; kk += 32) {
      const int ch = (kk >> 3) + (lane >> 4);       // chunk 0..7
      bf16x8 af[4], bf[4];
      #pragma unroll
      for (int i = 0; i < 4; ++i) {
        const int ra = wr + (i << 4) + (lane & 15);
        af[i] = *(const bf16x8*)(As + ra * 64 + ((ch ^ (ra & 7)) << 3));
      }
      #pragma unroll
      for (int j = 0; j < 4; ++j) {
        const int rb = wc + (j << 4) + (lane & 15);
        bf[j] = *(const bf16x8*)(Bs + rb * 64 + ((ch ^ (rb & 7)) << 3));
      }
      #pragma unroll
      for (int i = 0; i < 4; ++i)
        #pragma unroll
        for (int j = 0; j < 4; ++j)
          acc[i][j] = __builtin_amdgcn_mfma_f32_16x16x32_bf16(af[i], bf[j], acc[i][j], 0, 0, 0);
    }
    __syncthreads();
  }

  // epilogue: C/D layout col=lane&15, row=(lane>>4)*4+reg
  const int qrow = (lane >> 4) << 2;
  const int qcol = lane & 15;
  #pragma unroll
  for (int j = 0; j < 4; ++j) {
    const long col = tileN + wc + (j << 4) + qcol;
    const float bv = bias[col];
    #pragma unroll
    for (int i = 0; i < 4; ++i) {
      const long row0 = tileM + wr + (i << 4) + qrow;
      #pragma unroll
      for (int r = 0; r < 4; ++r) {
        const long off = (row0 + r) * N + col;
        const float z = acc[i][j][r] + bv;
        if constexpr (SIGMOID) {
          ((float*)Cout)[off] = sigmoidf(z);
        } else {
          ((u16*)Cout)[off] = f2bf(fmaxf(z, 0.f) * mask[off]);
        }
      }
    }
  }
}

// ---------------------------------------------------------------------------
extern "C" void kernel_launch(void* const* d_in, const int* in_sizes, int n_in,
                              void* d_out, int out_size, void* d_ws, size_t ws_size,
                              hipStream_t stream) {
  const int*   tok  = (const int*)  d_in[0];
  const float* E    = (const float*)d_in[1];
  const float* Wx   = (const float*)d_in[2];
  const float* U    = (const float*)d_in[3];
  const float* bvec = (const float*)d_in[4];
  const float* W1   = (const float*)d_in[5];
  const float* b1   = (const float*)d_in[6];
  const float* W1b  = (const float*)d_in[7];
  const float* W2   = (const float*)d_in[8];
  const float* b2   = (const float*)d_in[9];
  const float* recm = (const float*)d_in[10];
  const float* dm1  = (const float*)d_in[11];
  const float* dm2  = (const float*)d_in[12];
  float* out = (float*)d_out;

  char* w = (char*)d_ws;
  u16* Wt     = (u16*)w;  w += (size_t)Vc * Vc * 2;        // 128 MB (reused W1b/W2)
  u16* A1     = (u16*)w;  w += (size_t)Mrows * Vc * 2;     // 64 MB
  u16* A2     = (u16*)w;  w += (size_t)Mrows * Vc * 2;     // 64 MB
  u16* W1T    = (u16*)w;  w += (size_t)Vc * 64 * 2;        // 1 MB
  u16* pooled = (u16*)w;  w += (size_t)Mrows * 64 * 2;     // 0.5 MB
  float* zx   = (float*)w;                                  // 6.25 MB

  zx_kernel  <<<Bc * Tc, 256, 0, stream>>>(tok, E, Wx, bvec, zx);
  lstm_kernel<<<Bc, 256, 0, stream>>>(zx, U, recm, pooled);
  w1t_kernel <<<(Vc * 64) / 256, 256, 0, stream>>>(W1, W1T);
  // d1 = relu(pooled @ W1 + b1) * dmask1  -> A1 (bf16)
  gemm_bt<false><<<dim3(Vc / 128, Mrows / 128), 256, 0, stream>>>(
      pooled, W1T, b1, dm1, A1, Mrows, Vc, 64);
  // d2 = relu(A1 @ W1b + b1) * dmask2 -> A2 (bf16)
  wt_kernel<<<dim3(Vc / 64, Vc / 256), 256, 0, stream>>>(W1b, Wt);
  gemm_bt<false><<<dim3(Vc / 128, Mrows / 128), 256, 0, stream>>>(
      A1, Wt, b1, dm2, A2, Mrows, Vc, Vc);
  // prbs = sigmoid(A2 @ W2 + b2) -> out (f32)
  wt_kernel<<<dim3(Vc / 64, Vc / 256), 256, 0, stream>>>(W2, Wt);
  gemm_bt<true><<<dim3(Vc / 128, Mrows / 128), 256, 0, stream>>>(
      A2, Wt, b2, nullptr, out, Mrows, Vc, Vc);
}